// Round 3
// 511.921 us; speedup vs baseline: 1.1644x; 1.1644x over previous
//
#include <hip/hip_runtime.h>

typedef unsigned short u16;
using bf16x8 = __attribute__((ext_vector_type(8))) short;
using f32x4  = __attribute__((ext_vector_type(4))) float;

#define SQRT_HALF 0.70710678118f

__device__ __forceinline__ u16 f2bf(float f) {
    union { float f; unsigned int i; } x; x.f = f;
    unsigned int i = x.i;
    unsigned int r = (i + 0x7FFFu + ((i >> 16) & 1u)) >> 16;
    return (u16)r;
}
__device__ __forceinline__ float bf2f(u16 u) {
    union { unsigned int i; float f; } x; x.i = ((unsigned int)u) << 16; return x.f;
}
// v_rcp_f32 (~1 ulp) instead of full-precision fdiv: error << bf16 rounding.
__device__ __forceinline__ float fastrcp(float x) {
    float r; asm("v_rcp_f32 %0, %1" : "=v"(r) : "v"(x)); return r;
}
__device__ __forceinline__ float sigm(float x) {
    return fastrcp(1.0f + __expf(-x));
}
__device__ __forceinline__ float tanh_f(float x) {
    float cx = fminf(fmaxf(x, -12.f), 12.f);
    float e = __expf(2.f * cx);
    return 1.0f - 2.0f * fastrcp(e + 1.0f);   // (e-1)/(e+1)
}

// async global->LDS, 16B per lane; LDS dest is wave-uniform base + lane*16
// (chunk = i*256 + tid layout guarantees it).
__device__ __forceinline__ void gld16(const u16* g, u16* l) {
    __builtin_amdgcn_global_load_lds(
        (const __attribute__((address_space(1))) void*)g,
        (__attribute__((address_space(3))) void*)l,
        16, 0, 0);
}

// cond2[n][c] = tanh(mgc @ cond_w.T + cond_b) reshaped [400,60]  (all f32)
__global__ void cond_kernel(const float* __restrict__ mgc, const float* __restrict__ cond_w,
                            const float* __restrict__ cond_b, float* __restrict__ cond2) {
    int j = blockIdx.x * 256 + threadIdx.x;
    if (j >= 24000) return;
    int f = j / 12000, jj = j % 12000;
    float s = cond_b[jj];
    const float* wrow = cond_w + (size_t)jj * 60;
    const float* mrow = mgc + f * 60;
    for (int c = 0; c < 60; ++c) s += mrow[c] * wrow[c];
    float v = tanh_f(s);
    int n = f * 200 + jj / 60, cc = jj % 60;
    cond2[n * 60 + cc] = v;
}

// ca_in/ca_g[l][n][co] = cond2[n]·cw[l][co] + cb[l][co] + conv_bias(l,co)   (f32)
__global__ void condadd_kernel(const float* __restrict__ cond2,
                               const float* __restrict__ cw_in, const float* __restrict__ cb_in,
                               const float* __restrict__ cw_g,  const float* __restrict__ cb_g,
                               const float* __restrict__ l0_bin, const float* __restrict__ lb_in,
                               const float* __restrict__ l0_bg,  const float* __restrict__ lb_g,
                               float* __restrict__ ca_in, float* __restrict__ ca_g) {
    int idx = blockIdx.x * 256 + threadIdx.x;
    if (idx >= 10 * 400 * 256) return;
    int co = idx & 255;
    int n  = (idx >> 8) % 400;
    int l  = idx / (400 * 256);
    float si = cb_in[l * 256 + co] + (l == 0 ? l0_bin[co] : lb_in[(l - 1) * 256 + co]);
    float sg = cb_g [l * 256 + co] + (l == 0 ? l0_bg [co] : lb_g [(l - 1) * 256 + co]);
    const float* cn = cond2 + n * 60;
    const float* wi = cw_in + (size_t)(l * 256 + co) * 60;
    const float* wg = cw_g  + (size_t)(l * 256 + co) * 60;
    for (int c = 0; c < 60; ++c) {
        float cv = cn[c];
        si += cv * wi[c];
        sg += cv * wg[c];
    }
    ca_in[idx] = si;
    ca_g[idx]  = sg;
}

// Wg[l][conv][co][k*256+ci] = bf16(lw_conv[l][co][ci][k])
__global__ void wreorder_kernel(const float* __restrict__ lw_in, const float* __restrict__ lw_g,
                                const float* __restrict__ lw_r, u16* __restrict__ Wg) {
    int idx = blockIdx.x * 256 + threadIdx.x;
    if (idx >= 9 * 256 * 512) return;
    int kk = idx & 511;
    int co = (idx >> 9) & 255;
    int l  = idx >> 17;
    int k = kk >> 8, ci = kk & 255;
    size_t src = ((size_t)(l * 256 + co) * 256 + ci) * 2 + k;
    size_t dst = (size_t)l * 3 * 131072 + (size_t)co * 512 + kk;
    Wg[dst]              = f2bf(lw_in[src]);
    Wg[dst + 131072]     = f2bf(lw_g[src]);
    Wg[dst + 2 * 131072] = f2bf(lw_r[src]);
}

// Layer 0 (full f32 math): Y0[n_local][t][ci] bf16, t in [0,512)
__global__ void l0_kernel(const float* __restrict__ signal,
                          const float* __restrict__ l0_win, const float* __restrict__ l0_wg,
                          const float* __restrict__ l0_wr,  const float* __restrict__ l0_br,
                          const float* __restrict__ ca_in0, const float* __restrict__ ca_g0,
                          u16* __restrict__ Y0, int n_start) {
    int b = blockIdx.x;
    int tg = b & 127, n_local = b >> 7;
    int n = n_start + n_local;
    int ci = threadIdx.x;
    float wi0 = l0_win[ci * 2], wi1 = l0_win[ci * 2 + 1];
    float wg0 = l0_wg [ci * 2], wg1 = l0_wg [ci * 2 + 1];
    float wr0 = l0_wr [ci * 2], wr1 = l0_wr [ci * 2 + 1];
    float cain = ca_in0[n * 256 + ci], cag = ca_g0[n * 256 + ci], br = l0_br[ci];
    for (int i = 0; i < 4; ++i) {
        int t = tg * 4 + i;
        float s0 = signal[n + 2 * t];
        float s1 = signal[n + 2 * t + 1];
        float vin = wi0 * s0 + wi1 * s1 + cain;
        float vg  = wg0 * s0 + wg1 * s1 + cag;
        float vr  = wr0 * s0 + wr1 * s1 + br;
        float o = (tanh_f(vin) * sigm(vg) + vr) * SQRT_HALF;
        Y0[((size_t)n_local * 512 + t) * 256 + ci] = f2bf(o);
    }
}

// Fused 3-conv GEMM + gating, layers 1..9.
// A: [M,512] bf16 row-major. Wg: [3][256][512] bf16. Out: Y [M,256] bf16.
// Tile 128M x 64co x 3conv, BK=32, LDS 40 KB -> 3 blocks/CU.
// Staging: global_load_lds (16B/lane), linear LDS dest + inverse-swizzled
// global source; ds_read applies the XOR swizzle.
// Pipeline depth 2: counted s_waitcnt vmcnt(5), never drained to 0 mid-loop.
// Grid 1-D: the 4 co-tiles of one m-tile land on the SAME XCD (b%8
// preserved), dispatch-adjacent -> A panel fetched from HBM once per XCD.
__global__ __launch_bounds__(256, 3) void gemm_layer_kernel(
        const u16* __restrict__ A, const u16* __restrict__ Wg,
        const float* __restrict__ ca_in, const float* __restrict__ ca_g,
        const float* __restrict__ br, u16* __restrict__ Y,
        int M, int lg, int n_start) {
    __shared__ __attribute__((aligned(16))) u16 A0[128 * 32];
    __shared__ __attribute__((aligned(16))) u16 A1[128 * 32];
    __shared__ __attribute__((aligned(16))) u16 B0[192 * 32];
    __shared__ __attribute__((aligned(16))) u16 B1[192 * 32];

    int mtiles = (M + 127) >> 7;
    int b = blockIdx.x;
    int mtile, cotile;
    if ((mtiles & 7) == 0) {
        int g = b >> 5, r = b & 31;         // 32-block group = 8 mtiles x 4 cotiles
        mtile  = g * 8 + (r & 7);           // r&7 == b%8 == XCD id
        cotile = r >> 3;
    } else {
        mtile = b >> 2; cotile = b & 3;
    }
    int m0  = mtile * 128;
    int co0 = cotile * 64;
    int tid = threadIdx.x;
    int lane = tid & 63, wave = tid >> 6;
    int wm = wave & 1, wc = wave >> 1;
    int q = lane >> 4, r16 = lane & 15;

    // staging geometry: per thread 2 A-chunks + 3 B-chunks (16B each) per kt.
    // chunk c = i*256 + tid: row = c>>2, slot = c&3. LDS dest linear (c*16B);
    // global source column pre-swizzled by slot ^ ((row>>1)&3).
    const u16* agp[2]; unsigned aoff[2];
    #pragma unroll
    for (int i = 0; i < 2; ++i) {
        int c = i * 256 + tid;
        int row = c >> 2, s = c & 3;
        int m = m0 + row;
        int msafe = m < M ? m : (M - 1);
        agp[i] = A + (size_t)msafe * 512 + (s ^ ((row >> 1) & 3)) * 8;
        aoff[i] = (unsigned)c * 8;
    }
    const u16* bgp[3]; unsigned boff[3];
    #pragma unroll
    for (int i = 0; i < 3; ++i) {
        int c = i * 256 + tid;
        int row = c >> 2, s = c & 3;
        int conv = row >> 6, col = row & 63;
        bgp[i] = Wg + ((size_t)conv * 256 + co0 + col) * 512 + (s ^ ((row >> 1) & 3)) * 8;
        boff[i] = (unsigned)c * 8;
    }

    f32x4 acc[3][4][2] = {};

    auto doIssue = [&](int ktn, u16* Al, u16* Bl) {
        #pragma unroll
        for (int i = 0; i < 2; ++i) gld16(agp[i] + ktn * 32, &Al[aoff[i]]);
        #pragma unroll
        for (int i = 0; i < 3; ++i) gld16(bgp[i] + ktn * 32, &Bl[boff[i]]);
    };
    auto doComp = [&](const u16* Al, const u16* Bl) {
        bf16x8 af[4], bfr[3][2];
        #pragma unroll
        for (int ms = 0; ms < 4; ++ms) {
            int row = wm * 64 + ms * 16 + r16;
            af[ms] = *(const bf16x8*)(&Al[row * 32 + ((q ^ ((row >> 1) & 3)) * 8)]);
        }
        #pragma unroll
        for (int cv = 0; cv < 3; ++cv)
            #pragma unroll
            for (int cs = 0; cs < 2; ++cs) {
                int row = cv * 64 + wc * 32 + cs * 16 + r16;
                bfr[cv][cs] = *(const bf16x8*)(&Bl[row * 32 + ((q ^ ((row >> 1) & 3)) * 8)]);
            }
        __builtin_amdgcn_s_setprio(1);
        #pragma unroll
        for (int cv = 0; cv < 3; ++cv)
            #pragma unroll
            for (int ms = 0; ms < 4; ++ms)
                #pragma unroll
                for (int cs = 0; cs < 2; ++cs)
                    acc[cv][ms][cs] = __builtin_amdgcn_mfma_f32_16x16x32_bf16(
                        af[ms], bfr[cv][cs], acc[cv][ms][cs], 0, 0, 0);
        __builtin_amdgcn_s_setprio(0);
    };

    // prologue: batches 0 and 1 in flight; wait only batch 0 (vmcnt(5)).
    doIssue(0, A0, B0);
    doIssue(1, A1, B1);
    asm volatile("s_waitcnt vmcnt(5)\n\ts_barrier" ::: "memory");

    // main loop: 16 K-steps; separate LDS symbols so alias analysis never
    // forces a vmcnt(0) drain.
    #pragma unroll
    for (int kt2 = 0; kt2 < 7; ++kt2) {
        doComp(A0, B0);                                               // batch 2*kt2
        asm volatile("s_waitcnt lgkmcnt(0)\n\ts_barrier" ::: "memory"); // all waves done reading A0/B0
        doIssue(2 * kt2 + 2, A0, B0);
        asm volatile("s_waitcnt vmcnt(5)\n\ts_barrier" ::: "memory");   // batch 2*kt2+1 landed
        doComp(A1, B1);                                               // batch 2*kt2+1
        asm volatile("s_waitcnt lgkmcnt(0)\n\ts_barrier" ::: "memory");
        doIssue(2 * kt2 + 3, A1, B1);
        asm volatile("s_waitcnt vmcnt(5)\n\ts_barrier" ::: "memory");   // batch 2*kt2+2 landed
    }
    doComp(A0, B0);                                                   // batch 14
    asm volatile("s_waitcnt lgkmcnt(0)\n\ts_barrier" ::: "memory");
    asm volatile("s_waitcnt vmcnt(0)\n\ts_barrier" ::: "memory");     // drain batch 15
    doComp(A1, B1);                                                   // batch 15

    // epilogue: out = (tanh(in+ca_in) * sigmoid(g+ca_g) + r + br) * sqrt(0.5)
    #pragma unroll
    for (int ms = 0; ms < 4; ++ms) {
        #pragma unroll
        for (int reg = 0; reg < 4; ++reg) {
            int m = m0 + wm * 64 + ms * 16 + q * 4 + reg;
            if (m >= M) continue;
            int n = n_start + (m >> lg);
            #pragma unroll
            for (int cs = 0; cs < 2; ++cs) {
                int co = co0 + wc * 32 + cs * 16 + r16;
                float vin = acc[0][ms][cs][reg] + ca_in[n * 256 + co];
                float vg  = acc[1][ms][cs][reg] + ca_g [n * 256 + co];
                float vr  = acc[2][ms][cs][reg] + br[co];
                float o = (tanh_f(vin) * sigm(vg) + vr) * SQRT_HALF;
                Y[(size_t)m * 256 + co] = f2bf(o);
            }
        }
    }
}

// Head: pre = relu(Y9 @ pre_w.T + pre_b); mean/std/logits = pre @ W.T + b  (f32 math)
__global__ __launch_bounds__(256) void head_kernel(
        const u16* __restrict__ Y9, const float* __restrict__ pre_w, const float* __restrict__ pre_b,
        const float* __restrict__ mean_w, const float* __restrict__ mean_b,
        const float* __restrict__ std_w,  const float* __restrict__ std_b,
        const float* __restrict__ logit_w, const float* __restrict__ logit_b,
        float* __restrict__ out, int n_start) {
    __shared__ float xin[256];
    __shared__ float pre[256];
    int n_local = blockIdx.x;
    int n = n_start + n_local;
    int t = threadIdx.x;
    xin[t] = bf2f(Y9[(size_t)n_local * 256 + t]);
    __syncthreads();
    float s = pre_b[t];
    const float* wrow = pre_w + (size_t)t * 256;
    for (int c = 0; c < 256; ++c) s += xin[c] * wrow[c];
    pre[t] = fmaxf(s, 0.f);
    __syncthreads();
    if (t < 30) {
        int head = t / 10, mix = t % 10;
        const float* w  = head == 0 ? mean_w : (head == 1 ? std_w : logit_w);
        const float* bb = head == 0 ? mean_b : (head == 1 ? std_b : logit_b);
        float s2 = bb[mix];
        const float* wr = w + mix * 256;
        for (int c = 0; c < 256; ++c) s2 += pre[c] * wr[c];
        out[head * 4000 + n * 10 + mix] = s2;
    }
}

extern "C" void kernel_launch(void* const* d_in, const int* in_sizes, int n_in,
                              void* d_out, int out_size, void* d_ws, size_t ws_size,
                              hipStream_t stream) {
    const float* signal  = (const float*)d_in[0];
    const float* mgc     = (const float*)d_in[1];
    const float* cond_w  = (const float*)d_in[2];
    const float* cond_b  = (const float*)d_in[3];
    const float* l0_win  = (const float*)d_in[4];
    const float* l0_bin  = (const float*)d_in[5];
    const float* l0_wg   = (const float*)d_in[6];
    const float* l0_bg   = (const float*)d_in[7];
    const float* l0_wr   = (const float*)d_in[8];
    const float* l0_br   = (const float*)d_in[9];
    const float* lw_in   = (const float*)d_in[10];
    const float* lb_in   = (const float*)d_in[11];
    const float* lw_g    = (const float*)d_in[12];
    const float* lb_g    = (const float*)d_in[13];
    const float* lw_r    = (const float*)d_in[14];
    const float* lb_r    = (const float*)d_in[15];
    const float* cw_in   = (const float*)d_in[16];
    const float* cb_in   = (const float*)d_in[17];
    const float* cw_g    = (const float*)d_in[18];
    const float* cb_g    = (const float*)d_in[19];
    const float* pre_w   = (const float*)d_in[20];
    const float* pre_b   = (const float*)d_in[21];
    const float* mean_w  = (const float*)d_in[22];
    const float* mean_b  = (const float*)d_in[23];
    const float* std_w   = (const float*)d_in[24];
    const float* std_b   = (const float*)d_in[25];
    const float* logit_w = (const float*)d_in[26];
    const float* logit_b = (const float*)d_in[27];
    float* out = (float*)d_out;

    char* p = (char*)d_ws;
    auto alloc = [&](size_t bytes) -> char* {
        char* r = p; p += (bytes + 255) & ~(size_t)255; return r;
    };
    u16*   Wg    = (u16*)alloc(7077888);        // 9*3*256*512 bf16
    float* ca_in = (float*)alloc(4096000);      // 10*400*256 f32
    float* ca_g  = (float*)alloc(4096000);
    float* cond2 = (float*)alloc(96000);        // 400*60 f32
    size_t fixedBytes = (size_t)(p - (char*)d_ws);

    int c = 1;
    while (c < 16 && fixedBytes + (104857600ull + 52428800ull) / c + 4096 > ws_size) c <<= 1;
    u16* bufA = (u16*)alloc(104857600ull / c);
    u16* bufB = (u16*)alloc(52428800ull / c);
    int n_count = 400 / c;

    cond_kernel<<<94, 256, 0, stream>>>(mgc, cond_w, cond_b, cond2);
    condadd_kernel<<<4000, 256, 0, stream>>>(cond2, cw_in, cb_in, cw_g, cb_g,
                                             l0_bin, lb_in, l0_bg, lb_g, ca_in, ca_g);
    wreorder_kernel<<<4608, 256, 0, stream>>>(lw_in, lw_g, lw_r, Wg);

    for (int ch = 0; ch < c; ++ch) {
        int n_start = ch * n_count;
        l0_kernel<<<n_count * 128, 256, 0, stream>>>(signal, l0_win, l0_wg, l0_wr, l0_br,
                                                     ca_in, ca_g, bufA, n_start);
        u16* src = bufA;
        u16* dst = bufB;
        for (int layer = 1; layer <= 9; ++layer) {
            int lg = 9 - layer;          // L_out = 1 << lg
            int M = n_count << lg;
            int mtiles = (M + 127) / 128;
            gemm_layer_kernel<<<mtiles * 4, 256, 0, stream>>>(
                src, Wg + (size_t)(layer - 1) * 3 * 131072,
                ca_in + (size_t)layer * 102400, ca_g + (size_t)layer * 102400,
                lb_r + (layer - 1) * 256, dst, M, lg, n_start);
            u16* tswap = src; src = dst; dst = tswap;
        }
        head_kernel<<<n_count, 256, 0, stream>>>(src, pre_w, pre_b, mean_w, mean_b,
                                                 std_w, std_b, logit_w, logit_b, out, n_start);
    }
}